// Round 4
// baseline (194.246 us; speedup 1.0000x reference)
//
#include <hip/hip_runtime.h>
#include <stdint.h>

typedef uint32_t u32;
typedef uint64_t u64;

// BinaryNet on MI355X: everything after binarize() is {-1,0,+1}.
// Layer1 (9 taps, odd) -> exact +-1 per output -> 1 bit.
// Layer2 (36 taps, even) -> ternary -> (value bit, nonzero bit).
// All convs/FCs computed as XOR + popcount on packed sign bits.
//
// ws layout (u32 index) — footprint 324 bytes (ws[0..80]), the R1/R3-proven bound.
//   [0..3]   w1p[c]    : 9-bit, bit 3*ky+kx
//   [8..23]  w2q[d]    : u64, 36-bit, bit 12*ky+4*kx+c
//   [24..55] w3lo[e]   : u64, bits 0..63 of 72-bit, bit 8*(3*ky+kx)+d
//   [56..71] w3hi[e]   : u32, bits 64..71
//   [72..79] wf1[j]    : 16-bit, bit e
//   [80]     wf2       : 8-bit, bit j

// ---------------- weight prep (R3-passing logic, 1024 threads -> 2 rounds) ----------------
__global__ void prep_weights(const float* __restrict__ w1, const float* __restrict__ w2,
                             const float* __restrict__ w3, const float* __restrict__ wfc1,
                             const float* __restrict__ wfc2, u32* __restrict__ ws) {
  const int tid = threadIdx.x;
  if (tid < 81) ws[tid] = 0;
  __syncthreads();
  for (int i = tid; i < 1612; i += 1024) {
    if (i < 36) {                       // w1 [4][9]
      const int c = i / 9, k = i % 9;
      if (w1[i] < 0.f) atomicOr(&ws[c], 1u << k);
    } else if (i < 324) {               // w2 [8][4][3][3]
      const int j = i - 36, d = j / 36, r = j % 36;
      const int c = r / 9, t = r % 9, ky = t / 3, kx = t % 3;
      const int bp = 12 * ky + 4 * kx + c;
      if (w2[j] < 0.f) atomicOr(&ws[8 + 2 * d + (bp >> 5)], 1u << (bp & 31));
    } else if (i < 1476) {              // w3 [16][8][3][3]
      const int j = i - 324, e = j / 72, r = j % 72;
      const int d = r / 9, t = r % 9, ky = t / 3, kx = t % 3;
      const int bp = 8 * (3 * ky + kx) + d;
      if (w3[j] < 0.f) {
        if (bp < 64) atomicOr(&ws[24 + 2 * e + (bp >> 5)], 1u << (bp & 31));
        else         atomicOr(&ws[56 + e], 1u << (bp - 64));
      }
    } else if (i < 1604) {              // wfc1 [8][16]
      const int j = i - 1476, row = j / 16, e = j % 16;
      if (wfc1[j] < 0.f) atomicOr(&ws[72 + row], 1u << e);
    } else {                            // wfc2 [1][8]
      const int j = i - 1604;
      if (wfc2[j] < 0.f) atomicOr(&ws[80], 1u << j);
    }
  }
}

// ---------------- fused kernel: batched-ballot staging + R3-verified eval ----------------
__global__ __launch_bounds__(256) void binnet(const float* __restrict__ x,
                                              const u32* __restrict__ ws,
                                              float* __restrict__ out) {
  __shared__ u64 st[4][228];
  const int tid = threadIdx.x;
  const int wv = tid >> 6, lane = tid & 63;
  const int b = blockIdx.x;

  // wave wv stages its own 64 elements' 225 words; lane-coalesced dword loads.
  // Word t = ballot of signs of flat floats [(256b+64wv)*225 + 64t .. +63]
  // (bit i = lane i's float) — identical LDS content to the R3-passing kernel.
  const float* xw = x + (size_t)(b * 256 + wv * 64) * 225 + lane;
  if (lane < 3) st[wv][225 + lane] = 0;   // zero tail words (insurance)

  // 9 groups of 25: all 25 independent coalesced loads issue before any ballot
  // consumes them (no exec toggle inside the group) -> ~25 loads in flight/wave.
  #pragma unroll
  for (int j0 = 0; j0 < 225; j0 += 25) {
    float v[25];
    #pragma unroll
    for (int k = 0; k < 25; ++k) v[k] = xw[(j0 + k) * 64];
    u64 m[25];
    #pragma unroll
    for (int k = 0; k < 25; ++k) m[k] = __ballot(v[k] < 0.f);
    if (lane == 0) {
      #pragma unroll
      for (int k = 0; k < 25; ++k) st[wv][j0 + k] = m[k];
    }
  }
  __syncthreads();

  // ---- Eval: byte-identical to the R3-passing kernel ----
  const u64* stw = st[wv];
  const int f0 = 225 * lane;
  const int w0 = f0 >> 6;
  const int sh = f0 & 63;
  u64 Wd[5];
  #pragma unroll
  for (int i = 0; i < 5; ++i) Wd[i] = stw[w0 + i];
  u64 Bv[4];
  #pragma unroll
  for (int i = 0; i < 4; ++i)
    Bv[i] = (Wd[i] >> sh) | ((Wd[i + 1] << (63 - sh)) << 1);  // sh==0 -> 0 contribution

  // rows: rb[r] bit k = sign(x[b,0,r,k])
  u32 rb[15];
  #pragma unroll
  for (int r = 0; r < 15; ++r) {
    const int f = 15 * r, w = f >> 6, o = f & 63;
    u64 v = Bv[w] >> o;
    if (o > 49) v |= Bv[w + 1] << (64 - o);
    rb[r] = (u32)v & 0x7FFFu;
  }

  // ---- Layer 1: 4ch, 15x15 -> 7x7, 9 taps (always +-1 out) ----
  const u32 w1p0 = ws[0], w1p1 = ws[1], w1p2 = ws[2], w1p3 = ws[3];
  u64 a1[4] = {0, 0, 0, 0};  // bit 4*(7*oy+ox)+c, 1 = negative
  int pix = 0;
  #pragma unroll
  for (int oy = 0; oy < 7; ++oy) {
    const u32 r0 = rb[2 * oy], r1 = rb[2 * oy + 1], r2 = rb[2 * oy + 2];
    #pragma unroll
    for (int ox = 0; ox < 7; ++ox) {
      const u32 t9 = ((r0 >> (2 * ox)) & 7) | (((r1 >> (2 * ox)) & 7) << 3)
                   | (((r2 >> (2 * ox)) & 7) << 6);
      u32 nib = 0;
      nib |= (u32)(__popc(t9 ^ w1p0) >= 5) << 0;
      nib |= (u32)(__popc(t9 ^ w1p1) >= 5) << 1;
      nib |= (u32)(__popc(t9 ^ w1p2) >= 5) << 2;
      nib |= (u32)(__popc(t9 ^ w1p3) >= 5) << 3;
      a1[pix >> 4] |= (u64)nib << ((pix & 15) * 4);
      ++pix;
    }
  }

  // ---- Layer 2: 8ch, 7x7 -> 3x3, 36 taps (ternary out) ----
  const u64* w2qp = (const u64*)(ws + 8);
  u64 W2[8];
  #pragma unroll
  for (int d = 0; d < 8; ++d) W2[d] = w2qp[d];
  u64 v2lo = 0, nz2lo = 0; u32 v2hi = 0, nz2hi = 0;  // bit 8*(3*oy+ox)+d
  #pragma unroll
  for (int oy = 0; oy < 3; ++oy) {
    #pragma unroll
    for (int ox = 0; ox < 3; ++ox) {
      u64 T = 0;
      #pragma unroll
      for (int ky = 0; ky < 3; ++ky) {
        const int p = 4 * (7 * (2 * oy + ky) + 2 * ox);
        const int w = p >> 6, o = p & 63;
        u64 v = a1[w] >> o;
        if (o > 52) v |= a1[w + 1] << (64 - o);
        T |= (v & 0xFFFull) << (12 * ky);
      }
      const int pix2 = 3 * oy + ox;
      u32 bv = 0, bz = 0;
      #pragma unroll
      for (int d = 0; d < 8; ++d) {
        const int cnt = __popcll(T ^ W2[d]);  // #neg products of 36
        bv |= (u32)(cnt > 18) << d;           // sum = 36-2cnt < 0
        bz |= (u32)(cnt != 18) << d;          // nonzero
      }
      if (pix2 < 8) { v2lo |= (u64)bv << (8 * pix2); nz2lo |= (u64)bz << (8 * pix2); }
      else          { v2hi = bv; nz2hi = bz; }
    }
  }

  // ---- Layer 3: 16ch, 3x3 -> 1x1, 72 taps, ternary in/out ----
  const u64* w3lo = (const u64*)(ws + 24);
  const u32* w3hi = ws + 56;
  u64 W3L[16]; u32 W3H[16];
  #pragma unroll
  for (int e = 0; e < 16; ++e) { W3L[e] = w3lo[e]; W3H[e] = w3hi[e]; }
  const int nztot = __popcll(nz2lo) + __popc(nz2hi);
  u32 s3v = 0, s3nz = 0;
  #pragma unroll
  for (int e = 0; e < 16; ++e) {
    const int cnt = __popcll(nz2lo & (v2lo ^ W3L[e])) + __popc(nz2hi & (v2hi ^ W3H[e]));
    const int s = nztot - 2 * cnt;
    s3v  |= (u32)(s < 0) << e;
    s3nz |= (u32)(s != 0) << e;
  }

  // ---- FC1: 16 -> 8, ternary ----
  const u32* wf1 = ws + 72;
  u32 WF1[8];
  #pragma unroll
  for (int j = 0; j < 8; ++j) WF1[j] = wf1[j];
  const int n3 = __popc(s3nz);
  u32 hv = 0, hz = 0;
  #pragma unroll
  for (int j = 0; j < 8; ++j) {
    const int c2 = __popc(s3nz & (s3v ^ WF1[j]));
    const int s = n3 - 2 * c2;
    hv |= (u32)(s < 0) << j;
    hz |= (u32)(s != 0) << j;
  }

  // ---- FC2: 8 -> 1 (no hardtanh) ----
  const u32 wf2 = ws[80];
  const int c3 = __popc(hz & (hv ^ wf2));
  const int sfin = __popc(hz) - 2 * c3;
  out[b * 256 + wv * 64 + lane] = (float)sfin;
}

extern "C" void kernel_launch(void* const* d_in, const int* in_sizes, int n_in,
                              void* d_out, int out_size, void* d_ws, size_t ws_size,
                              hipStream_t stream) {
  const float* x    = (const float*)d_in[0];
  const float* w1   = (const float*)d_in[1];
  const float* w2   = (const float*)d_in[2];
  const float* w3   = (const float*)d_in[3];
  const float* wfc1 = (const float*)d_in[4];
  const float* wfc2 = (const float*)d_in[5];
  u32* ws = (u32*)d_ws;
  float* out = (float*)d_out;
  const int B = in_sizes[0] / 225;  // 131072

  prep_weights<<<1, 1024, 0, stream>>>(w1, w2, w3, wfc1, wfc2, ws);
  binnet<<<B / 256, 256, 0, stream>>>(x, ws, out);
}

// Round 6
// 189.563 us; speedup vs baseline: 1.0247x; 1.0247x over previous
//
#include <hip/hip_runtime.h>
#include <stdint.h>

typedef uint32_t u32;
typedef uint64_t u64;

// BinaryNet on MI355X: everything after binarize() is {-1,0,+1}.
// Layer1 (9 taps, odd) -> exact +-1 per output -> 1 bit.
// Layer2 (36 taps, even) -> ternary -> (value bit, nonzero bit).
// All convs/FCs computed as XOR + popcount on packed sign bits.
//
// Launch-shape policy: every <<<512,256>>> config passed bit-exact (R1/R3/R4);
// both attempts to scale the launch shape (R2: 2048-block producer, R5:
// 1024-thread blocks) died with identical ~2^32 absmax signatures. Staying in
// the proven envelope; latency is attacked with ILP (deep load batches), which
// R4 accidentally defeated by buffering 25 u64 ballots (75+ live VGPRs vs the
// compiler's 64-VGPR occupancy target -> batch collapse -> serial rounds).
// Here: 45 plain float loads per group (~55 live VGPRs), ballot+LDS-store
// immediately per word -> all 45 loads in flight, fine-grained vmcnt drain.
//
// ws layout (u32 index) — footprint 324 bytes (ws[0..80]).
//   [0..3]   w1p[c]    : 9-bit, bit 3*ky+kx
//   [8..23]  w2q[d]    : u64, 36-bit, bit 12*ky+4*kx+c
//   [24..55] w3lo[e]   : u64, bits 0..63 of 72-bit, bit 8*(3*ky+kx)+d
//   [56..71] w3hi[e]   : u32, bits 64..71
//   [72..79] wf1[j]    : 16-bit, bit e
//   [80]     wf2       : 8-bit, bit j

// ---------------- weight prep (R3/R4-passing logic, unchanged) ----------------
__global__ void prep_weights(const float* __restrict__ w1, const float* __restrict__ w2,
                             const float* __restrict__ w3, const float* __restrict__ wfc1,
                             const float* __restrict__ wfc2, u32* __restrict__ ws) {
  const int tid = threadIdx.x;
  if (tid < 81) ws[tid] = 0;
  __syncthreads();
  for (int i = tid; i < 1612; i += 1024) {
    if (i < 36) {                       // w1 [4][9]
      const int c = i / 9, k = i % 9;
      if (w1[i] < 0.f) atomicOr(&ws[c], 1u << k);
    } else if (i < 324) {               // w2 [8][4][3][3]
      const int j = i - 36, d = j / 36, r = j % 36;
      const int c = r / 9, t = r % 9, ky = t / 3, kx = t % 3;
      const int bp = 12 * ky + 4 * kx + c;
      if (w2[j] < 0.f) atomicOr(&ws[8 + 2 * d + (bp >> 5)], 1u << (bp & 31));
    } else if (i < 1476) {              // w3 [16][8][3][3]
      const int j = i - 324, e = j / 72, r = j % 72;
      const int d = r / 9, t = r % 9, ky = t / 3, kx = t % 3;
      const int bp = 8 * (3 * ky + kx) + d;
      if (w3[j] < 0.f) {
        if (bp < 64) atomicOr(&ws[24 + 2 * e + (bp >> 5)], 1u << (bp & 31));
        else         atomicOr(&ws[56 + e], 1u << (bp - 64));
      }
    } else if (i < 1604) {              // wfc1 [8][16]
      const int j = i - 1476, row = j / 16, e = j % 16;
      if (wfc1[j] < 0.f) atomicOr(&ws[72 + row], 1u << e);
    } else {                            // wfc2 [1][8]
      const int j = i - 1604;
      if (wfc2[j] < 0.f) atomicOr(&ws[80], 1u << j);
    }
  }
}

// ---------------- fused kernel: deep-batch ballot staging + verified eval ----------------
__global__ __launch_bounds__(256) void binnet(const float* __restrict__ x,
                                              const u32* __restrict__ ws,
                                              float* __restrict__ out) {
  __shared__ u64 st[4][228];
  const int tid = threadIdx.x;
  const int wv = tid >> 6, lane = tid & 63;
  const int b = blockIdx.x;

  // Wave wv stages its own 64 elements' 225 sign words (flat float order):
  // word t = ballot over lanes of float [(256b+64wv)*225 + 64t + lane].
  // 5 groups of 45: all 45 coalesced loads issue before the ballot/store
  // drain (45 live floats ~ 55 VGPRs, fits the compiler's 64-VGPR target).
  const float* xw = x + (size_t)(b * 256 + wv * 64) * 225 + lane;
  if (lane < 3) st[wv][225 + lane] = 0;   // zero tail words
  #pragma unroll
  for (int g = 0; g < 5; ++g) {
    float v[45];
    #pragma unroll
    for (int k = 0; k < 45; ++k) v[k] = xw[(g * 45 + k) * 64];
    #pragma unroll
    for (int k = 0; k < 45; ++k) {
      const u64 m = __ballot(v[k] < 0.f);
      if (lane == 0) st[wv][g * 45 + k] = m;
    }
  }
  __syncthreads();

  // ---- Eval: byte-identical to the R3/R4-passing kernel ----
  const u64* stw = st[wv];
  const int f0 = 225 * lane;
  const int w0 = f0 >> 6;
  const int sh = f0 & 63;
  u64 Wd[5];
  #pragma unroll
  for (int i = 0; i < 5; ++i) Wd[i] = stw[w0 + i];
  u64 Bv[4];
  #pragma unroll
  for (int i = 0; i < 4; ++i)
    Bv[i] = (Wd[i] >> sh) | ((Wd[i + 1] << (63 - sh)) << 1);  // sh==0 -> 0 contribution

  // rows: rb[r] bit k = sign(x[b,0,r,k])
  u32 rb[15];
  #pragma unroll
  for (int r = 0; r < 15; ++r) {
    const int f = 15 * r, w = f >> 6, o = f & 63;
    u64 v = Bv[w] >> o;
    if (o > 49) v |= Bv[w + 1] << (64 - o);
    rb[r] = (u32)v & 0x7FFFu;
  }

  // ---- Layer 1: 4ch, 15x15 -> 7x7, 9 taps (always +-1 out) ----
  const u32 w1p0 = ws[0], w1p1 = ws[1], w1p2 = ws[2], w1p3 = ws[3];
  u64 a1[4] = {0, 0, 0, 0};  // bit 4*(7*oy+ox)+c, 1 = negative
  int pix = 0;
  #pragma unroll
  for (int oy = 0; oy < 7; ++oy) {
    const u32 r0 = rb[2 * oy], r1 = rb[2 * oy + 1], r2 = rb[2 * oy + 2];
    #pragma unroll
    for (int ox = 0; ox < 7; ++ox) {
      const u32 t9 = ((r0 >> (2 * ox)) & 7) | (((r1 >> (2 * ox)) & 7) << 3)
                   | (((r2 >> (2 * ox)) & 7) << 6);
      u32 nib = 0;
      nib |= (u32)(__popc(t9 ^ w1p0) >= 5) << 0;
      nib |= (u32)(__popc(t9 ^ w1p1) >= 5) << 1;
      nib |= (u32)(__popc(t9 ^ w1p2) >= 5) << 2;
      nib |= (u32)(__popc(t9 ^ w1p3) >= 5) << 3;
      a1[pix >> 4] |= (u64)nib << ((pix & 15) * 4);
      ++pix;
    }
  }

  // ---- Layer 2: 8ch, 7x7 -> 3x3, 36 taps (ternary out) ----
  const u64* w2qp = (const u64*)(ws + 8);
  u64 W2[8];
  #pragma unroll
  for (int d = 0; d < 8; ++d) W2[d] = w2qp[d];
  u64 v2lo = 0, nz2lo = 0; u32 v2hi = 0, nz2hi = 0;  // bit 8*(3*oy+ox)+d
  #pragma unroll
  for (int oy = 0; oy < 3; ++oy) {
    #pragma unroll
    for (int ox = 0; ox < 3; ++ox) {
      u64 T = 0;
      #pragma unroll
      for (int ky = 0; ky < 3; ++ky) {
        const int p = 4 * (7 * (2 * oy + ky) + 2 * ox);
        const int w = p >> 6, o = p & 63;
        u64 v = a1[w] >> o;
        if (o > 52) v |= a1[w + 1] << (64 - o);
        T |= (v & 0xFFFull) << (12 * ky);
      }
      const int pix2 = 3 * oy + ox;
      u32 bv = 0, bz = 0;
      #pragma unroll
      for (int d = 0; d < 8; ++d) {
        const int cnt = __popcll(T ^ W2[d]);  // #neg products of 36
        bv |= (u32)(cnt > 18) << d;           // sum = 36-2cnt < 0
        bz |= (u32)(cnt != 18) << d;          // nonzero
      }
      if (pix2 < 8) { v2lo |= (u64)bv << (8 * pix2); nz2lo |= (u64)bz << (8 * pix2); }
      else          { v2hi = bv; nz2hi = bz; }
    }
  }

  // ---- Layer 3: 16ch, 3x3 -> 1x1, 72 taps, ternary in/out ----
  const u64* w3lo = (const u64*)(ws + 24);
  const u32* w3hi = ws + 56;
  u64 W3L[16]; u32 W3H[16];
  #pragma unroll
  for (int e = 0; e < 16; ++e) { W3L[e] = w3lo[e]; W3H[e] = w3hi[e]; }
  const int nztot = __popcll(nz2lo) + __popc(nz2hi);
  u32 s3v = 0, s3nz = 0;
  #pragma unroll
  for (int e = 0; e < 16; ++e) {
    const int cnt = __popcll(nz2lo & (v2lo ^ W3L[e])) + __popc(nz2hi & (v2hi ^ W3H[e]));
    const int s = nztot - 2 * cnt;
    s3v  |= (u32)(s < 0) << e;
    s3nz |= (u32)(s != 0) << e;
  }

  // ---- FC1: 16 -> 8, ternary ----
  const u32* wf1 = ws + 72;
  u32 WF1[8];
  #pragma unroll
  for (int j = 0; j < 8; ++j) WF1[j] = wf1[j];
  const int n3 = __popc(s3nz);
  u32 hv = 0, hz = 0;
  #pragma unroll
  for (int j = 0; j < 8; ++j) {
    const int c2 = __popc(s3nz & (s3v ^ WF1[j]));
    const int s = n3 - 2 * c2;
    hv |= (u32)(s < 0) << j;
    hz |= (u32)(s != 0) << j;
  }

  // ---- FC2: 8 -> 1 (no hardtanh) ----
  const u32 wf2 = ws[80];
  const int c3 = __popc(hz & (hv ^ wf2));
  const int sfin = __popc(hz) - 2 * c3;
  out[b * 256 + wv * 64 + lane] = (float)sfin;
}

extern "C" void kernel_launch(void* const* d_in, const int* in_sizes, int n_in,
                              void* d_out, int out_size, void* d_ws, size_t ws_size,
                              hipStream_t stream) {
  const float* x    = (const float*)d_in[0];
  const float* w1   = (const float*)d_in[1];
  const float* w2   = (const float*)d_in[2];
  const float* w3   = (const float*)d_in[3];
  const float* wfc1 = (const float*)d_in[4];
  const float* wfc2 = (const float*)d_in[5];
  u32* ws = (u32*)d_ws;
  float* out = (float*)d_out;
  const int B = in_sizes[0] / 225;  // 131072

  prep_weights<<<1, 1024, 0, stream>>>(w1, w2, w3, wfc1, wfc2, ws);
  binnet<<<B / 256, 256, 0, stream>>>(x, ws, out);
}